// Round 11
// baseline (1103.212 us; speedup 1.0000x reference)
//
#include <hip/hip_runtime.h>
#include <hip/hip_bf16.h>
#include <math.h>
#include <stdint.h>

// Problem constants
constexpr int N_ROWS = 32768;
constexpr int K_DIM  = 4096;
constexpr int R_DIM  = 256;
constexpr int KP     = 3 * R_DIM;   // 768: split-K' for [hi|hi|lo] x [hi|lo|hi]
constexpr int KB     = K_DIM / 128; // 32 col-blocks in K2 grid

typedef __bf16 bf16x8 __attribute__((ext_vector_type(8)));
typedef float  f32x4  __attribute__((ext_vector_type(4)));
typedef unsigned short u16x8 __attribute__((ext_vector_type(8)));
typedef unsigned short u16x4 __attribute__((ext_vector_type(4)));

// ---- bf16 helpers (round-to-nearest-even; inputs are finite normals) ----
__device__ __forceinline__ unsigned short f2bf(float x) {
    unsigned u = __float_as_uint(x);
    u += 0x7fffu + ((u >> 16) & 1u);
    return (unsigned short)(u >> 16);
}
__device__ __forceinline__ float bf2f(unsigned short h) {
    return __uint_as_float((unsigned)h << 16);
}

// ---- async global->LDS, 16B per lane, LDS dest = wave-uniform base + lane*16
__device__ __forceinline__ void gl2lds16(const void* gptr, void* lptr) {
    __builtin_amdgcn_global_load_lds(
        (const __attribute__((address_space(1))) unsigned int*)gptr,
        (__attribute__((address_space(3))) unsigned int*)lptr,
        16, 0, 0);
}

// ===========================================================================
// K2: logits over A'(bf16 split) x B'^T. 128x128 tile, BK=32, 4 waves.
// Grid: 1-D, yb innermost (R10-proven). LDS chunks (16 rows x 32 elems) are
// XOR-swizzled within row quads: slot j of row r holds global 8-elem group
// j ^ ((r>>1)&3)  [rule #21: inverse-swizzled gl2lds SOURCE + swizzled read].
// Fragment-read bank pairs (r&1, q^((r>>1)&3)) span 8 groups over 16 lanes ->
// 2-way (free, m136) instead of 8-way; zero cost, layout/occupancy identical.
// Epilogue (single-exp): block max, then ONE exp pass -> e16 + Ps partials.
// ===========================================================================
__global__ __launch_bounds__(256)
void gemm_mfma_nt(const unsigned short* __restrict__ A,
                  const unsigned short* __restrict__ B,
                  float* __restrict__ Mout,
                  float* __restrict__ Pm, float* __restrict__ Ps,
                  int M, int N, int Kc)
{
    __shared__ __align__(16) unsigned short As[128 * 32];
    __shared__ __align__(16) unsigned short Bs[128 * 32];
    __shared__ float pm_s[128][2], ps_s[128][2];
    __shared__ float pmc[128];

    const int tid  = threadIdx.x;
    const int wave = tid >> 6, lane = tid & 63;
    const int wm = wave >> 1, wn = wave & 1;

    // bijective 1-D decode: bid = xg*1024 + xi*32 + yb  (yb innermost)
    const int bid = blockIdx.x;
    const int xg = bid >> 10;          // row super-group 0..7
    const int xi = (bid >> 5) & 31;    // row-panel within group
    const int yb = bid & 31;           // col-panel     0..31
    const long m0 = (long)(xg * 32 + xi) * 128;
    const long n0 = (long)yb * 128;

    f32x4 acc[4][4] = {};

    const int srow  = lane >> 2;        // 0..15 within 16-row chunk
    // swizzled source elem offset: slot (l&3) of row (l>>2) loads global
    // 8-group (l&3) ^ ((row>>1)&3) = (l&3) ^ ((l>>3)&3)
    const int skoff = (((lane & 3) ^ ((lane >> 3) & 3)) * 8);
    const int c0 = wave, c1 = wave + 4; // each wave stages 2 chunks per tile
    const int mr = lane & 15;
    // swizzled fragment-read slot: global q = lane>>4 lives at slot
    // q ^ ((row>>1)&3) = q ^ ((mr>>1)&3)   (row = wm*64+t*16+mr; 16,64 = 0 mod 4... row>>1 & 3 = ((t*8 + (mr>>1)) & 3) = (mr>>1)&3)
    const int kqs = (((lane >> 4) ^ ((mr >> 1) & 3)) * 8);

    for (int k0 = 0; k0 < Kc; k0 += 32) {
        gl2lds16(A + (m0 + c0 * 16 + srow) * (long)Kc + k0 + skoff, &As[c0 * 512]);
        gl2lds16(A + (m0 + c1 * 16 + srow) * (long)Kc + k0 + skoff, &As[c1 * 512]);
        gl2lds16(B + (n0 + c0 * 16 + srow) * (long)Kc + k0 + skoff, &Bs[c0 * 512]);
        gl2lds16(B + (n0 + c1 * 16 + srow) * (long)Kc + k0 + skoff, &Bs[c1 * 512]);
        __syncthreads();

        bf16x8 af[4], bfr[4];
#pragma unroll
        for (int t = 0; t < 4; ++t) {
            af[t]  = *(const bf16x8*)&As[(wm * 64 + t * 16 + mr) * 32 + kqs];
            bfr[t] = *(const bf16x8*)&Bs[(wn * 64 + t * 16 + mr) * 32 + kqs];
        }
#pragma unroll
        for (int i = 0; i < 4; ++i)
#pragma unroll
            for (int j = 0; j < 4; ++j)
                acc[i][j] = __builtin_amdgcn_mfma_f32_16x16x32_bf16(
                    af[i], bfr[j], acc[i][j], 0, 0, 0);
        __syncthreads();
    }

    const int col = lane & 15, rquad = (lane >> 4) * 4;

    // ---- pass 1: wave-half max per row -> block max (pmc) + Pm -------------
#pragma unroll
    for (int i = 0; i < 4; ++i) {
#pragma unroll
        for (int r = 0; r < 4; ++r) {
            float mx = fmaxf(fmaxf(acc[i][0][r], acc[i][1][r]),
                             fmaxf(acc[i][2][r], acc[i][3][r]));
#pragma unroll
            for (int off = 1; off < 16; off <<= 1)
                mx = fmaxf(mx, __shfl_xor(mx, off));
            if (mr == 0) pm_s[wm * 64 + i * 16 + rquad + r][wn] = mx;
        }
    }
    __syncthreads();
    if (tid < 128) {
        const float mx = fmaxf(pm_s[tid][0], pm_s[tid][1]);
        pmc[tid] = mx;
        Pm[(m0 + tid) * KB + yb] = mx;
    }
    __syncthreads();

    // ---- pass 2: single exp pass -> e16 write + Ps sum partials ------------
    unsigned short* E = (unsigned short*)Mout;
#pragma unroll
    for (int i = 0; i < 4; ++i) {
#pragma unroll
        for (int r = 0; r < 4; ++r) {
            const int rw = wm * 64 + i * 16 + rquad + r;
            const float mx = pmc[rw];
            const float e0 = __expf(acc[i][0][r] - mx);
            const float e1 = __expf(acc[i][1][r] - mx);
            const float e2 = __expf(acc[i][2][r] - mx);
            const float e3 = __expf(acc[i][3][r] - mx);
            unsigned short* ep =
                E + (m0 + rw) * 8192L + 4096 + n0 + wn * 64 + col;
            ep[0]  = f2bf(e0); ep[16] = f2bf(e1);
            ep[32] = f2bf(e2); ep[48] = f2bf(e3);
            float sm = (e0 + e1) + (e2 + e3);
#pragma unroll
            for (int off = 1; off < 16; off <<= 1)
                sm += __shfl_xor(sm, off);
            if (mr == 0) ps_s[rw][wn] = sm;
        }
    }
    __syncthreads();
    if (tid < 128)
        Ps[(m0 + tid) * KB + yb] = ps_s[tid][0] + ps_s[tid][1];
}

// ===========================================================================
// Combine per-block softmax partials -> per-row (max, 1/sum) AND rewrite
// Ps in place as CS[n][b] = exp(Pm[n][b] - m_n) * inv_n (av_pv's rescales).
// ===========================================================================
__global__ __launch_bounds__(256)
void finalize_ms(const float* __restrict__ Pm, float* __restrict__ Ps,
                 float* __restrict__ SMm, float* __restrict__ SMi)
{
    const long row = (long)blockIdx.x * 256 + threadIdx.x;
    const float4* pm = (const float4*)(Pm + row * KB);
    float4* ps = (float4*)(Ps + row * KB);
    float4 v[8], w[8];
    float mx = -3.4e38f;
#pragma unroll
    for (int q = 0; q < 8; ++q) {
        v[q] = pm[q];
        w[q] = ps[q];
        mx = fmaxf(mx, fmaxf(fmaxf(v[q].x, v[q].y), fmaxf(v[q].z, v[q].w)));
    }
    float s = 0.f;
#pragma unroll
    for (int q = 0; q < 8; ++q) {
        s += w[q].x * __expf(v[q].x - mx) + w[q].y * __expf(v[q].y - mx) +
             w[q].z * __expf(v[q].z - mx) + w[q].w * __expf(v[q].w - mx);
    }
    const float inv = 1.f / s;
    SMm[row] = mx;
    SMi[row] = inv;
#pragma unroll
    for (int q = 0; q < 8; ++q) {
        float4 c;
        c.x = __expf(v[q].x - mx) * inv;
        c.y = __expf(v[q].y - mx) * inv;
        c.z = __expf(v[q].z - mx) * inv;
        c.w = __expf(v[q].w - mx) * inv;
        ps[q] = c;
    }
}

// ===========================================================================
// Fused softmax-apply + PV from e16 — 2-phase double-buffered pipeline
// (R8-proven, best measured):
//   A[n,k] = bf2f(e16[n,k]) * CS[n][k/128]   (fp32, written over Aout rows)
//   C[n,r] = sum_k A[n,k] * LT[r,k]          (bf16 MFMA, A already normalized)
// Per tile t: {stage Bs[nxt] (t+1), emit As[nxt] (t+1) from prefetched e16,
// prefetch e16(t+2), MFMA(cur)} then ONE barrier. 64 barriers total.
// LDS 80 KiB -> 2 blocks/CU (grid 512 = 2/CU).
// Aliasing (A-writes clobber e16 upper half): per-thread row ownership;
// every e16 prefetch is reg-resident (drained by the iteration barrier)
// before the emit that clobbers its memory.
// ===========================================================================
__global__ __launch_bounds__(512, 4)
void softmax_av_pv(float* Aout,                      // NOT restrict: aliases e16
                   const unsigned short* __restrict__ LT,
                   const float* __restrict__ CS,
                   float* __restrict__ C)
{
    __shared__ __align__(16) unsigned short Bs[2][R_DIM * 64]; // 64 KiB (swizzled)
    __shared__ __align__(16) unsigned short As[2][64 * 64];    // 16 KiB (swizzled)

    const int tid  = threadIdx.x;
    const int wave = tid >> 6, lane = tid & 63;
    const long m0 = (long)blockIdx.x * 64;

    const int wm = wave >> 2, wn = wave & 3;  // wave tile: 32 rows x 64 cols
    const int mr = lane & 15;
    const int kq16 = (lane >> 4) * 16;

    // A-emit mapping: each thread owns 2 rows, 4 cols
    const int arow0 = wave * 4 + (lane >> 4);
    const int arow1 = 32 + arow0;
    const int acolE = (lane & 15) * 4;
    const unsigned short* const ep0 =
        (const unsigned short*)Aout + (m0 + arow0) * 8192L + 4096 + acolE;
    const unsigned short* const ep1 =
        (const unsigned short*)Aout + (m0 + arow1) * 8192L + 4096 + acolE;
    float* const gp0 = Aout + (m0 + arow0) * (long)K_DIM + acolE;
    float* const gp1 = Aout + (m0 + arow1) * (long)K_DIM + acolE;
    const int ab0 = (arow0 * 128 + acolE * 2) ^ ((arow0 & 7) << 4);
    const int ab1 = (arow1 * 128 + acolE * 2) ^ ((arow1 & 7) << 4);
    const float* const cs0 = CS + (m0 + arow0) * KB;
    const float* const cs1 = CS + (m0 + arow1) * KB;

    f32x4 acc[2][4] = {};
    constexpr int NT = K_DIM / 64;   // 64 tiles

    // stage LT k-tile into Bs[buf] (source pre-swizzled, dest linear)
    auto stage_B = [&](int buf, int k0) {
#pragma unroll
        for (int q = 0; q < 4; ++q) {
            const int rbase = q * 64 + wave * 8;
            const int rloc  = rbase + (lane >> 3);
            const int phys  = (lane & 7) * 16;
            const int kbyte = phys ^ ((rloc & 7) << 4);
            gl2lds16((const char*)LT + (long)rloc * (K_DIM * 2) + (long)k0 * 2 + kbyte,
                     &Bs[buf][rbase * 64]);
        }
    };
    // emit tile t1 into As[buf] from e16 regs: scale by CS, A-write, LDS bf16
    auto emit_A = [&](int buf, int t1, u16x4 va0, u16x4 va1) {
        const int b  = t1 >> 1;
        const int k0 = t1 * 64;
        const float c0 = cs0[b], c1 = cs1[b];
        float a0 = bf2f(va0[0]) * c0, a1 = bf2f(va0[1]) * c0;
        float a2 = bf2f(va0[2]) * c0, a3 = bf2f(va0[3]) * c0;
        *(float4*)(gp0 + k0) = make_float4(a0, a1, a2, a3);
        u16x4 u0;
        u0[0] = f2bf(a0); u0[1] = f2bf(a1); u0[2] = f2bf(a2); u0[3] = f2bf(a3);
        *(u16x4*)((char*)As[buf] + ab0) = u0;

        float b0 = bf2f(va1[0]) * c1, b1 = bf2f(va1[1]) * c1;
        float b2 = bf2f(va1[2]) * c1, b3 = bf2f(va1[3]) * c1;
        *(float4*)(gp1 + k0) = make_float4(b0, b1, b2, b3);
        u16x4 u1;
        u1[0] = f2bf(b0); u1[1] = f2bf(b1); u1[2] = f2bf(b2); u1[3] = f2bf(b3);
        *(u16x4*)((char*)As[buf] + ab1) = u1;
    };

    // --- prologue: tile 0 staged + emitted; e16(1) prefetched ---------------
    stage_B(0, 0);
    {
        u16x4 e0a = *(const u16x4*)ep0;
        u16x4 e0b = *(const u16x4*)ep1;
        emit_A(0, 0, e0a, e0b);
    }
    u16x4 va0 = *(const u16x4*)(ep0 + 64);   // e16(1)
    u16x4 va1 = *(const u16x4*)(ep1 + 64);
    __syncthreads();

    for (int t = 0; t < NT; ++t) {
        const int cur = t & 1, nxt = cur ^ 1;
        if (t + 1 < NT) {
            stage_B(nxt, (t + 1) * 64);
            emit_A(nxt, t + 1, va0, va1);
        }
        if (t + 2 < NT) {
            va0 = *(const u16x4*)(ep0 + (t + 2) * 64);
            va1 = *(const u16x4*)(ep1 + (t + 2) * 64);
        }

        // ---- MFMA on cur: 2x4 tiles x 2 k-slices ---------------------------
#pragma unroll
        for (int ks = 0; ks < 2; ++ks) {
            bf16x8 af[2], bfr[4];
#pragma unroll
            for (int tt = 0; tt < 2; ++tt) {
                const int ar = wm * 32 + tt * 16 + mr;
                const int ab = (ar * 128 + ks * 64 + kq16) ^ ((ar & 7) << 4);
                af[tt] = *(const bf16x8*)((const char*)As[cur] + ab);
            }
#pragma unroll
            for (int tt = 0; tt < 4; ++tt) {
                const int br = wn * 64 + tt * 16 + mr;
                const int bb = (br * 128 + ks * 64 + kq16) ^ ((br & 7) << 4);
                bfr[tt] = *(const bf16x8*)((const char*)Bs[cur] + bb);
            }
#pragma unroll
            for (int i = 0; i < 2; ++i)
#pragma unroll
                for (int j = 0; j < 4; ++j)
                    acc[i][j] = __builtin_amdgcn_mfma_f32_16x16x32_bf16(
                        af[i], bfr[j], acc[i][j], 0, 0, 0);
        }
        __syncthreads();   // single barrier per tile (drains stage + prefetch)
    }

    // ---- epilogue: A was already normalized -> C = acc directly ------------
    const int col = lane & 15, rquad = (lane >> 4) * 4;
#pragma unroll
    for (int i = 0; i < 2; ++i) {
        const int lrow0 = wm * 32 + i * 16 + rquad;
#pragma unroll
        for (int j = 0; j < 4; ++j) {
            float* p = C + (m0 + lrow0) * (long)R_DIM + wn * 64 + j * 16 + col;
#pragma unroll
            for (int r = 0; r < 4; ++r)
                p[(long)r * R_DIM] = acc[i][j][r];
        }
    }
}

// ===========================================================================
// Prep kernels
// ===========================================================================
// B' = [L_hi | L_lo | L_hi]  (K_DIM x 768)
__global__ __launch_bounds__(256)
void prep_B(const float* __restrict__ L, unsigned short* __restrict__ Bp)
{
    const long i = (long)blockIdx.x * 256 + threadIdx.x;   // over K_DIM*R_DIM
    const long k = i >> 8; const int r = (int)(i & 255);
    const float x = L[i];
    const unsigned short hi = f2bf(x);
    const unsigned short lo = f2bf(x - bf2f(hi));
    unsigned short* row = Bp + k * KP;
    row[r] = hi; row[R_DIM + r] = lo; row[2 * R_DIM + r] = hi;
}

// LT[r][k] = bf16(L[k][r])  (256 x 4096) — coalesced writes
__global__ __launch_bounds__(256)
void prep_LT(const float* __restrict__ L, unsigned short* __restrict__ LT)
{
    const long i = (long)blockIdx.x * 256 + threadIdx.x;   // over R_DIM*K_DIM
    const long r = i >> 12; const long k = i & 4095;
    LT[r * K_DIM + k] = f2bf(L[k * R_DIM + r]);
}

// ===========================================================================
// fp32 VALU GEMM — K1 base + fallback path.
// ===========================================================================
template<bool BT>
__global__ __launch_bounds__(256)
void gemm128(const float* __restrict__ A, const float* __restrict__ B,
             float* __restrict__ C, int M, int N, int Kc)
{
    __shared__ __align__(16) float Asl[16][132];
    __shared__ __align__(16) float Bsl[16][132];

    const int tid = threadIdx.x;
    const int tx = tid & 15, ty = tid >> 4;
    const long m0 = (long)blockIdx.x * 128;
    const long n0 = (long)blockIdx.y * 128;

    float acc[8][8];
#pragma unroll
    for (int i = 0; i < 8; ++i)
#pragma unroll
        for (int j = 0; j < 8; ++j) acc[i][j] = 0.f;

    for (int k0 = 0; k0 < Kc; k0 += 16) {
#pragma unroll
        for (int q = 0; q < 2; ++q) {
            int fi = tid + 256 * q, row = fi >> 2, col = (fi & 3) * 4;
            float4 v = *(const float4*)(A + (m0 + row) * (long)Kc + k0 + col);
            Asl[col + 0][row] = v.x; Asl[col + 1][row] = v.y;
            Asl[col + 2][row] = v.z; Asl[col + 3][row] = v.w;
        }
        if (BT) {
#pragma unroll
            for (int q = 0; q < 2; ++q) {
                int fi = tid + 256 * q, row = fi >> 2, col = (fi & 3) * 4;
                float4 v = *(const float4*)(B + (n0 + row) * (long)Kc + k0 + col);
                Bsl[col + 0][row] = v.x; Bsl[col + 1][row] = v.y;
                Bsl[col + 2][row] = v.z; Bsl[col + 3][row] = v.w;
            }
        } else {
#pragma unroll
            for (int q = 0; q < 2; ++q) {
                int fi = tid + 256 * q, row = fi >> 5, col = (fi & 31) * 4;
                float4 v = *(const float4*)(B + (k0 + row) * (long)N + n0 + col);
                *(float4*)&Bsl[row][col] = v;
            }
        }
        __syncthreads();
#pragma unroll
        for (int kk = 0; kk < 16; ++kk) {
            float a[8], b[8];
            *(float4*)&a[0] = *(const float4*)&Asl[kk][ty * 8];
            *(float4*)&a[4] = *(const float4*)&Asl[kk][ty * 8 + 4];
            *(float4*)&b[0] = *(const float4*)&Bsl[kk][tx * 8];
            *(float4*)&b[4] = *(const float4*)&Bsl[kk][tx * 8 + 4];
#pragma unroll
            for (int i = 0; i < 8; ++i)
#pragma unroll
                for (int j = 0; j < 8; ++j)
                    acc[i][j] = fmaf(a[i], b[j], acc[i][j]);
        }
        __syncthreads();
    }
#pragma unroll
    for (int i = 0; i < 8; ++i) {
        float* p = C + (m0 + ty * 8 + i) * (long)N + n0 + tx * 8;
        *(float4*)p       = make_float4(acc[i][0], acc[i][1], acc[i][2], acc[i][3]);
        *(float4*)(p + 4) = make_float4(acc[i][4], acc[i][5], acc[i][6], acc[i][7]);
    }
}

// ===========================================================================
// K1 with fused split-write: P = A@B (fp32 VALU), epilogue writes
// Ap = [P_hi | P_hi | P_lo] directly (no P materialization).
// ===========================================================================
__global__ __launch_bounds__(256)
void gemm128_hl(const float* __restrict__ A, const float* __restrict__ B,
                unsigned short* __restrict__ Ap, int M, int N, int Kc)
{
    __shared__ __align__(16) float Asl[16][132];
    __shared__ __align__(16) float Bsl[16][132];

    const int tid = threadIdx.x;
    const int tx = tid & 15, ty = tid >> 4;
    const long m0 = (long)blockIdx.x * 128;
    const long n0 = (long)blockIdx.y * 128;

    float acc[8][8];
#pragma unroll
    for (int i = 0; i < 8; ++i)
#pragma unroll
        for (int j = 0; j < 8; ++j) acc[i][j] = 0.f;

    for (int k0 = 0; k0 < Kc; k0 += 16) {
#pragma unroll
        for (int q = 0; q < 2; ++q) {
            int fi = tid + 256 * q, row = fi >> 2, col = (fi & 3) * 4;
            float4 v = *(const float4*)(A + (m0 + row) * (long)Kc + k0 + col);
            Asl[col + 0][row] = v.x; Asl[col + 1][row] = v.y;
            Asl[col + 2][row] = v.z; Asl[col + 3][row] = v.w;
        }
#pragma unroll
        for (int q = 0; q < 2; ++q) {
            int fi = tid + 256 * q, row = fi >> 5, col = (fi & 31) * 4;
            float4 v = *(const float4*)(B + (k0 + row) * (long)N + n0 + col);
            *(float4*)&Bsl[row][col] = v;
        }
        __syncthreads();
#pragma unroll
        for (int kk = 0; kk < 16; ++kk) {
            float a[8], b[8];
            *(float4*)&a[0] = *(const float4*)&Asl[kk][ty * 8];
            *(float4*)&a[4] = *(const float4*)&Asl[kk][ty * 8 + 4];
            *(float4*)&b[0] = *(const float4*)&Bsl[kk][tx * 8];
            *(float4*)&b[4] = *(const float4*)&Bsl[kk][tx * 8 + 4];
#pragma unroll
            for (int i = 0; i < 8; ++i)
#pragma unroll
                for (int j = 0; j < 8; ++j)
                    acc[i][j] = fmaf(a[i], b[j], acc[i][j]);
        }
        __syncthreads();
    }
#pragma unroll
    for (int i = 0; i < 8; ++i) {
        const long row = m0 + ty * 8 + i;
        const int  cb  = (int)n0 + tx * 8;
        u16x8 vh, vl;
#pragma unroll
        for (int j = 0; j < 8; ++j) {
            const float x = acc[i][j];
            const unsigned short hi = f2bf(x);
            vh[j] = hi;
            vl[j] = f2bf(x - bf2f(hi));
        }
        unsigned short* rp = Ap + row * KP;
        *(u16x8*)(rp + cb)             = vh;
        *(u16x8*)(rp + R_DIM + cb)     = vh;
        *(u16x8*)(rp + 2 * R_DIM + cb) = vl;
    }
}

// ---------------------------------------------------------------------------
// In-place row softmax (fallback path only)
// ---------------------------------------------------------------------------
__global__ __launch_bounds__(256)
void softmax_rows(float* __restrict__ Mio)
{
    const long n  = blockIdx.x;
    float* row    = Mio + n * (long)K_DIM;
    const int tid = threadIdx.x;

    float4 v[4];
    float lmax = -3.4e38f;
#pragma unroll
    for (int q = 0; q < 4; ++q) {
        v[q] = ((const float4*)row)[tid + 256 * q];
        lmax = fmaxf(lmax, fmaxf(fmaxf(v[q].x, v[q].y), fmaxf(v[q].z, v[q].w)));
    }
    __shared__ float redmax[4], redsum[4];
#pragma unroll
    for (int off = 32; off > 0; off >>= 1)
        lmax = fmaxf(lmax, __shfl_xor(lmax, off));
    if ((tid & 63) == 0) redmax[tid >> 6] = lmax;
    __syncthreads();
    const float gmax = fmaxf(fmaxf(redmax[0], redmax[1]), fmaxf(redmax[2], redmax[3]));

    float lsum = 0.f;
#pragma unroll
    for (int q = 0; q < 4; ++q) {
        v[q].x = __expf(v[q].x - gmax); v[q].y = __expf(v[q].y - gmax);
        v[q].z = __expf(v[q].z - gmax); v[q].w = __expf(v[q].w - gmax);
        lsum += v[q].x + v[q].y + v[q].z + v[q].w;
    }
#pragma unroll
    for (int off = 32; off > 0; off >>= 1)
        lsum += __shfl_xor(lsum, off);
    if ((tid & 63) == 0) redsum[tid >> 6] = lsum;
    __syncthreads();
    const float inv = 1.f / (redsum[0] + redsum[1] + redsum[2] + redsum[3]);
#pragma unroll
    for (int q = 0; q < 4; ++q) {
        v[q].x *= inv; v[q].y *= inv; v[q].z *= inv; v[q].w *= inv;
        ((float4*)row)[tid + 256 * q] = v[q];
    }
}

// ===========================================================================
extern "C" void kernel_launch(void* const* d_in, const int* in_sizes, int n_in,
                              void* d_out, int out_size, void* d_ws, size_t ws_size,
                              hipStream_t stream)
{
    const float* H  = (const float*)d_in[0];
    const float* L  = (const float*)d_in[1];
    const float* Wi = (const float*)d_in[2];

    float* Cout = (float*)d_out;                           // N x R
    float* Aout = (float*)d_out + (size_t)N_ROWS * R_DIM;  // N x K

    const size_t szAp = (size_t)N_ROWS * KP * 2;    // 48 MiB
    const size_t szBp = (size_t)K_DIM * KP * 2;     //  6 MiB
    const size_t szLT = (size_t)R_DIM * K_DIM * 2;  //  2 MiB
    const size_t szPm = (size_t)N_ROWS * KB * 4;    //  4 MiB
    const size_t szPs = (size_t)N_ROWS * KB * 4;    //  4 MiB
    const size_t szSM = (size_t)N_ROWS * 4;         // 128 KiB

    if (ws_size >= szAp + szBp + szLT + szPm + szPs + 2 * szSM) {
        char* w = (char*)d_ws;
        unsigned short* Ap = (unsigned short*)w;                 w += szAp;
        unsigned short* Bp = (unsigned short*)w;                 w += szBp;
        unsigned short* LT = (unsigned short*)w;                 w += szLT;
        float* Pm  = (float*)w;                                  w += szPm;
        float* Ps  = (float*)w;                                  w += szPs;
        float* SMm = (float*)w;                                  w += szSM;
        float* SMi = (float*)w;

        // K1: P = H@W_I (fp32 VALU), split [hi|hi|lo] written directly to Ap
        gemm128_hl<<<dim3(N_ROWS / 128, R_DIM / 128), 256, 0, stream>>>(
            H, Wi, Ap, N_ROWS, R_DIM, R_DIM);
        // Prep split B operand + transposed bf16 L
        prep_B<<<dim3((K_DIM * R_DIM) / 256), 256, 0, stream>>>(L, Bp);
        prep_LT<<<dim3((R_DIM * K_DIM) / 256), 256, 0, stream>>>(L, LT);
        // K2: logits (3-term split bf16 MFMA) -> e16 + softmax partials
        // yb-innermost traversal + chunk XOR-swizzle (bank-conflict-free)
        gemm_mfma_nt<<<dim3((N_ROWS / 128) * (K_DIM / 128)), 256, 0, stream>>>(
            Ap, Bp, Aout, Pm, Ps, N_ROWS, K_DIM, KP);
        // combine partials -> per-row stats; Ps rewritten in place as CS
        finalize_ms<<<dim3(N_ROWS / 256), 256, 0, stream>>>(Pm, Ps, SMm, SMi);
        // fused softmax-apply + PV from e16 (R8 2-phase double-buffered)
        softmax_av_pv<<<dim3(N_ROWS / 64), 512, 0, stream>>>(
            Aout, LT, Ps, Cout);
    } else {
        // Fallback: round-1 fp32 path
        gemm128<false><<<dim3(N_ROWS / 128, R_DIM / 128), 256, 0, stream>>>(
            H, Wi, Cout, N_ROWS, R_DIM, R_DIM);
        gemm128<true><<<dim3(N_ROWS / 128, K_DIM / 128), 256, 0, stream>>>(
            Cout, L, Aout, N_ROWS, K_DIM, R_DIM);
        softmax_rows<<<dim3(N_ROWS), 256, 0, stream>>>(Aout);
        gemm128<false><<<dim3(N_ROWS / 128, R_DIM / 128), 256, 0, stream>>>(
            Aout, L, Cout, N_ROWS, R_DIM, K_DIM);
    }
}

// Round 13
// 1094.782 us; speedup vs baseline: 1.0077x; 1.0077x over previous
//
#include <hip/hip_runtime.h>
#include <hip/hip_bf16.h>
#include <math.h>
#include <stdint.h>

// Problem constants
constexpr int N_ROWS = 32768;
constexpr int K_DIM  = 4096;
constexpr int R_DIM  = 256;
constexpr int KP     = 3 * R_DIM;   // 768: split-K' for [hi|hi|lo] x [hi|lo|hi]
constexpr int KB     = K_DIM / 128; // 32 col-blocks in K2 grid

typedef __bf16 bf16x8 __attribute__((ext_vector_type(8)));
typedef float  f32x4  __attribute__((ext_vector_type(4)));
typedef unsigned short u16x8 __attribute__((ext_vector_type(8)));
typedef unsigned short u16x4 __attribute__((ext_vector_type(4)));

// ---- bf16 helpers (round-to-nearest-even; inputs are finite normals) ----
__device__ __forceinline__ unsigned short f2bf(float x) {
    unsigned u = __float_as_uint(x);
    u += 0x7fffu + ((u >> 16) & 1u);
    return (unsigned short)(u >> 16);
}
__device__ __forceinline__ float bf2f(unsigned short h) {
    return __uint_as_float((unsigned)h << 16);
}

// ---- async global->LDS, 16B per lane, LDS dest = wave-uniform base + lane*16
__device__ __forceinline__ void gl2lds16(const void* gptr, void* lptr) {
    __builtin_amdgcn_global_load_lds(
        (const __attribute__((address_space(1))) unsigned int*)gptr,
        (__attribute__((address_space(3))) unsigned int*)lptr,
        16, 0, 0);
}

// ===========================================================================
// K2: logits over A'(bf16 split) x B'^T. 128x128 tile, BK=32, 4 waves.
// Grid: 1-D, yb innermost (R10-proven). LDS chunks (16 rows x 32 elems) are
// XOR-swizzled within row quads (R11-proven: bank conflicts 2.5e7 -> 0).
// Epilogue (single-exp): block max, then ONE exp pass -> e16 + Ps partials.
// ===========================================================================
__global__ __launch_bounds__(256)
void gemm_mfma_nt(const unsigned short* __restrict__ A,
                  const unsigned short* __restrict__ B,
                  float* __restrict__ Mout,
                  float* __restrict__ Pm, float* __restrict__ Ps,
                  int M, int N, int Kc)
{
    __shared__ __align__(16) unsigned short As[128 * 32];
    __shared__ __align__(16) unsigned short Bs[128 * 32];
    __shared__ float pm_s[128][2], ps_s[128][2];
    __shared__ float pmc[128];

    const int tid  = threadIdx.x;
    const int wave = tid >> 6, lane = tid & 63;
    const int wm = wave >> 1, wn = wave & 1;

    // bijective 1-D decode: bid = xg*1024 + xi*32 + yb  (yb innermost)
    const int bid = blockIdx.x;
    const int xg = bid >> 10;          // row super-group 0..7
    const int xi = (bid >> 5) & 31;    // row-panel within group
    const int yb = bid & 31;           // col-panel     0..31
    const long m0 = (long)(xg * 32 + xi) * 128;
    const long n0 = (long)yb * 128;

    f32x4 acc[4][4] = {};

    const int srow  = lane >> 2;        // 0..15 within 16-row chunk
    // swizzled source elem offset: slot (l&3) of row (l>>2) loads global
    // 8-group (l&3) ^ ((row>>1)&3) = (l&3) ^ ((l>>3)&3)
    const int skoff = (((lane & 3) ^ ((lane >> 3) & 3)) * 8);
    const int c0 = wave, c1 = wave + 4; // each wave stages 2 chunks per tile
    const int mr = lane & 15;
    // swizzled fragment-read slot: global q = lane>>4 lives at slot q^((mr>>1)&3)
    const int kqs = (((lane >> 4) ^ ((mr >> 1) & 3)) * 8);

    for (int k0 = 0; k0 < Kc; k0 += 32) {
        gl2lds16(A + (m0 + c0 * 16 + srow) * (long)Kc + k0 + skoff, &As[c0 * 512]);
        gl2lds16(A + (m0 + c1 * 16 + srow) * (long)Kc + k0 + skoff, &As[c1 * 512]);
        gl2lds16(B + (n0 + c0 * 16 + srow) * (long)Kc + k0 + skoff, &Bs[c0 * 512]);
        gl2lds16(B + (n0 + c1 * 16 + srow) * (long)Kc + k0 + skoff, &Bs[c1 * 512]);
        __syncthreads();

        bf16x8 af[4], bfr[4];
#pragma unroll
        for (int t = 0; t < 4; ++t) {
            af[t]  = *(const bf16x8*)&As[(wm * 64 + t * 16 + mr) * 32 + kqs];
            bfr[t] = *(const bf16x8*)&Bs[(wn * 64 + t * 16 + mr) * 32 + kqs];
        }
#pragma unroll
        for (int i = 0; i < 4; ++i)
#pragma unroll
            for (int j = 0; j < 4; ++j)
                acc[i][j] = __builtin_amdgcn_mfma_f32_16x16x32_bf16(
                    af[i], bfr[j], acc[i][j], 0, 0, 0);
        __syncthreads();
    }

    const int col = lane & 15, rquad = (lane >> 4) * 4;

    // ---- pass 1: wave-half max per row -> block max (pmc) + Pm -------------
#pragma unroll
    for (int i = 0; i < 4; ++i) {
#pragma unroll
        for (int r = 0; r < 4; ++r) {
            float mx = fmaxf(fmaxf(acc[i][0][r], acc[i][1][r]),
                             fmaxf(acc[i][2][r], acc[i][3][r]));
#pragma unroll
            for (int off = 1; off < 16; off <<= 1)
                mx = fmaxf(mx, __shfl_xor(mx, off));
            if (mr == 0) pm_s[wm * 64 + i * 16 + rquad + r][wn] = mx;
        }
    }
    __syncthreads();
    if (tid < 128) {
        const float mx = fmaxf(pm_s[tid][0], pm_s[tid][1]);
        pmc[tid] = mx;
        Pm[(m0 + tid) * KB + yb] = mx;
    }
    __syncthreads();

    // ---- pass 2: single exp pass -> e16 write + Ps sum partials ------------
    unsigned short* E = (unsigned short*)Mout;
#pragma unroll
    for (int i = 0; i < 4; ++i) {
#pragma unroll
        for (int r = 0; r < 4; ++r) {
            const int rw = wm * 64 + i * 16 + rquad + r;
            const float mx = pmc[rw];
            const float e0 = __expf(acc[i][0][r] - mx);
            const float e1 = __expf(acc[i][1][r] - mx);
            const float e2 = __expf(acc[i][2][r] - mx);
            const float e3 = __expf(acc[i][3][r] - mx);
            unsigned short* ep =
                E + (m0 + rw) * 8192L + 4096 + n0 + wn * 64 + col;
            ep[0]  = f2bf(e0); ep[16] = f2bf(e1);
            ep[32] = f2bf(e2); ep[48] = f2bf(e3);
            float sm = (e0 + e1) + (e2 + e3);
#pragma unroll
            for (int off = 1; off < 16; off <<= 1)
                sm += __shfl_xor(sm, off);
            if (mr == 0) ps_s[rw][wn] = sm;
        }
    }
    __syncthreads();
    if (tid < 128)
        Ps[(m0 + tid) * KB + yb] = ps_s[tid][0] + ps_s[tid][1];
}

// ===========================================================================
// Combine per-block softmax partials -> per-row (max, 1/sum) AND rewrite
// Ps in place as CS[n][b] = exp(Pm[n][b] - m_n) * inv_n (av_pv's rescales).
// ===========================================================================
__global__ __launch_bounds__(256)
void finalize_ms(const float* __restrict__ Pm, float* __restrict__ Ps,
                 float* __restrict__ SMm, float* __restrict__ SMi)
{
    const long row = (long)blockIdx.x * 256 + threadIdx.x;
    const float4* pm = (const float4*)(Pm + row * KB);
    float4* ps = (float4*)(Ps + row * KB);
    float4 v[8], w[8];
    float mx = -3.4e38f;
#pragma unroll
    for (int q = 0; q < 8; ++q) {
        v[q] = pm[q];
        w[q] = ps[q];
        mx = fmaxf(mx, fmaxf(fmaxf(v[q].x, v[q].y), fmaxf(v[q].z, v[q].w)));
    }
    float s = 0.f;
#pragma unroll
    for (int q = 0; q < 8; ++q) {
        s += w[q].x * __expf(v[q].x - mx) + w[q].y * __expf(v[q].y - mx) +
             w[q].z * __expf(v[q].z - mx) + w[q].w * __expf(v[q].w - mx);
    }
    const float inv = 1.f / s;
    SMm[row] = mx;
    SMi[row] = inv;
#pragma unroll
    for (int q = 0; q < 8; ++q) {
        float4 c;
        c.x = __expf(v[q].x - mx) * inv;
        c.y = __expf(v[q].y - mx) * inv;
        c.z = __expf(v[q].z - mx) * inv;
        c.w = __expf(v[q].w - mx) * inv;
        ps[q] = c;
    }
}

// ===========================================================================
// Fused softmax-apply + PV from e16 — 2-phase pipeline with COUNTED vmcnt
// (T4, m218). FIXED vs R12's failing version:
//  (1) prefetch is UNCONDITIONAL with clamped index -> every iteration
//      issues exactly 8 vmem ops (4 stage + 2 store + 2 load), so vmcnt(4)
//      always retires precisely the 4 stage ops (R12 bug: tail iteration
//      issued only 6, leaving 2 stages un-retired -> corrupt last tile);
//  (2) sched_barrier(0) after the stage group PINS the 4 gl2lds as the
//      oldest vmem ops of the iteration (issue-order premise enforced).
// Steady-state walk-through: emit's register use of the t-1 prefetch forces
// (in-order vmcnt retirement) all t-1 ops complete; outstanding at the
// barrier is exactly {4 stages, 2 stores, 2 loads}; vmcnt(4) retires stages;
// stores+loads stay in flight ACROSS the barrier (the point of T4).
// lgkmcnt(0) covers emit's ds_writes. LDS 80 KiB -> 2 blocks/CU.
// ===========================================================================
__global__ __launch_bounds__(512, 4)
void softmax_av_pv(float* Aout,                      // NOT restrict: aliases e16
                   const unsigned short* __restrict__ LT,
                   const float* __restrict__ CS,
                   float* __restrict__ C)
{
    __shared__ __align__(16) unsigned short Bs[2][R_DIM * 64]; // 64 KiB (swizzled)
    __shared__ __align__(16) unsigned short As[2][64 * 64];    // 16 KiB (swizzled)

    const int tid  = threadIdx.x;
    const int wave = tid >> 6, lane = tid & 63;
    const long m0 = (long)blockIdx.x * 64;

    const int wm = wave >> 2, wn = wave & 3;  // wave tile: 32 rows x 64 cols
    const int mr = lane & 15;
    const int kq16 = (lane >> 4) * 16;

    // A-emit mapping: each thread owns 2 rows, 4 cols
    const int arow0 = wave * 4 + (lane >> 4);
    const int arow1 = 32 + arow0;
    const int acolE = (lane & 15) * 4;
    const unsigned short* const ep0 =
        (const unsigned short*)Aout + (m0 + arow0) * 8192L + 4096 + acolE;
    const unsigned short* const ep1 =
        (const unsigned short*)Aout + (m0 + arow1) * 8192L + 4096 + acolE;
    float* const gp0 = Aout + (m0 + arow0) * (long)K_DIM + acolE;
    float* const gp1 = Aout + (m0 + arow1) * (long)K_DIM + acolE;
    const int ab0 = (arow0 * 128 + acolE * 2) ^ ((arow0 & 7) << 4);
    const int ab1 = (arow1 * 128 + acolE * 2) ^ ((arow1 & 7) << 4);
    const float* const cs0 = CS + (m0 + arow0) * KB;
    const float* const cs1 = CS + (m0 + arow1) * KB;

    f32x4 acc[2][4] = {};
    constexpr int NT = K_DIM / 64;   // 64 tiles

    // stage LT k-tile into Bs[buf] (source pre-swizzled, dest linear)
    auto stage_B = [&](int buf, int k0) {
#pragma unroll
        for (int q = 0; q < 4; ++q) {
            const int rbase = q * 64 + wave * 8;
            const int rloc  = rbase + (lane >> 3);
            const int phys  = (lane & 7) * 16;
            const int kbyte = phys ^ ((rloc & 7) << 4);
            gl2lds16((const char*)LT + (long)rloc * (K_DIM * 2) + (long)k0 * 2 + kbyte,
                     &Bs[buf][rbase * 64]);
        }
    };
    // emit tile t1 into As[buf] from e16 regs: scale by CS, A-write, LDS bf16
    auto emit_A = [&](int buf, int t1, u16x4 va0, u16x4 va1) {
        const int b  = t1 >> 1;
        const int k0 = t1 * 64;
        const float c0 = cs0[b], c1 = cs1[b];
        float a0 = bf2f(va0[0]) * c0, a1 = bf2f(va0[1]) * c0;
        float a2 = bf2f(va0[2]) * c0, a3 = bf2f(va0[3]) * c0;
        *(float4*)(gp0 + k0) = make_float4(a0, a1, a2, a3);
        u16x4 u0;
        u0[0] = f2bf(a0); u0[1] = f2bf(a1); u0[2] = f2bf(a2); u0[3] = f2bf(a3);
        *(u16x4*)((char*)As[buf] + ab0) = u0;

        float b0 = bf2f(va1[0]) * c1, b1 = bf2f(va1[1]) * c1;
        float b2 = bf2f(va1[2]) * c1, b3 = bf2f(va1[3]) * c1;
        *(float4*)(gp1 + k0) = make_float4(b0, b1, b2, b3);
        u16x4 u1;
        u1[0] = f2bf(b0); u1[1] = f2bf(b1); u1[2] = f2bf(b2); u1[3] = f2bf(b3);
        *(u16x4*)((char*)As[buf] + ab1) = u1;
    };
    // counted-vmcnt barrier: the 4 stage ops (pinned oldest) retire; the
    // 2 stores + 2 prefetch loads (newest 4) may stay in flight.
    auto pipe_barrier = [&]() {
        asm volatile("s_waitcnt vmcnt(4) lgkmcnt(0)" ::: "memory");
        __builtin_amdgcn_s_barrier();
        __builtin_amdgcn_sched_barrier(0);
    };

    // --- prologue: tile 0 staged + emitted; e16(1) prefetched ---------------
    stage_B(0, 0);
    __builtin_amdgcn_sched_barrier(0);
    {
        u16x4 e0a = *(const u16x4*)ep0;
        u16x4 e0b = *(const u16x4*)ep1;
        emit_A(0, 0, e0a, e0b);
    }
    u16x4 va0 = *(const u16x4*)(ep0 + 64);   // e16(1)
    u16x4 va1 = *(const u16x4*)(ep1 + 64);
    pipe_barrier();

    for (int t = 0; t < NT; ++t) {
        const int cur = t & 1, nxt = cur ^ 1;
        if (t + 1 < NT) {
            stage_B(nxt, (t + 1) * 64);
            __builtin_amdgcn_sched_barrier(0);   // pin: stages issue first
            emit_A(nxt, t + 1, va0, va1);
        }
        // unconditional clamped prefetch keeps the vmcnt accounting uniform
        // (8 vmem ops/iter); tail loads are in-bounds and simply unconsumed.
        {
            const int tp = (t + 2 < NT) ? (t + 2) : (NT - 1);
            va0 = *(const u16x4*)(ep0 + tp * 64);
            va1 = *(const u16x4*)(ep1 + tp * 64);
        }

        // ---- MFMA on cur: 2x4 tiles x 2 k-slices ---------------------------
#pragma unroll
        for (int ks = 0; ks < 2; ++ks) {
            bf16x8 af[2], bfr[4];
#pragma unroll
            for (int tt = 0; tt < 2; ++tt) {
                const int ar = wm * 32 + tt * 16 + mr;
                const int ab = (ar * 128 + ks * 64 + kq16) ^ ((ar & 7) << 4);
                af[tt] = *(const bf16x8*)((const char*)As[cur] + ab);
            }
#pragma unroll
            for (int tt = 0; tt < 4; ++tt) {
                const int br = wn * 64 + tt * 16 + mr;
                const int bb = (br * 128 + ks * 64 + kq16) ^ ((br & 7) << 4);
                bfr[tt] = *(const bf16x8*)((const char*)Bs[cur] + bb);
            }
#pragma unroll
            for (int i = 0; i < 2; ++i)
#pragma unroll
                for (int j = 0; j < 4; ++j)
                    acc[i][j] = __builtin_amdgcn_mfma_f32_16x16x32_bf16(
                        af[i], bfr[j], acc[i][j], 0, 0, 0);
        }
        pipe_barrier();    // counted: stages done, stores/prefetch in flight
    }

    // ---- epilogue: A was already normalized -> C = acc directly ------------
    const int col = lane & 15, rquad = (lane >> 4) * 4;
#pragma unroll
    for (int i = 0; i < 2; ++i) {
        const int lrow0 = wm * 32 + i * 16 + rquad;
#pragma unroll
        for (int j = 0; j < 4; ++j) {
            float* p = C + (m0 + lrow0) * (long)R_DIM + wn * 64 + j * 16 + col;
#pragma unroll
            for (int r = 0; r < 4; ++r)
                p[(long)r * R_DIM] = acc[i][j][r];
        }
    }
}

// ===========================================================================
// Prep kernels
// ===========================================================================
// B' = [L_hi | L_lo | L_hi]  (K_DIM x 768)
__global__ __launch_bounds__(256)
void prep_B(const float* __restrict__ L, unsigned short* __restrict__ Bp)
{
    const long i = (long)blockIdx.x * 256 + threadIdx.x;   // over K_DIM*R_DIM
    const long k = i >> 8; const int r = (int)(i & 255);
    const float x = L[i];
    const unsigned short hi = f2bf(x);
    const unsigned short lo = f2bf(x - bf2f(hi));
    unsigned short* row = Bp + k * KP;
    row[r] = hi; row[R_DIM + r] = lo; row[2 * R_DIM + r] = hi;
}

// LT[r][k] = bf16(L[k][r])  (256 x 4096) — coalesced writes
__global__ __launch_bounds__(256)
void prep_LT(const float* __restrict__ L, unsigned short* __restrict__ LT)
{
    const long i = (long)blockIdx.x * 256 + threadIdx.x;   // over R_DIM*K_DIM
    const long r = i >> 12; const long k = i & 4095;
    LT[r * K_DIM + k] = f2bf(L[k * R_DIM + r]);
}

// ===========================================================================
// fp32 VALU GEMM — K1 base + fallback path.
// ===========================================================================
template<bool BT>
__global__ __launch_bounds__(256)
void gemm128(const float* __restrict__ A, const float* __restrict__ B,
             float* __restrict__ C, int M, int N, int Kc)
{
    __shared__ __align__(16) float Asl[16][132];
    __shared__ __align__(16) float Bsl[16][132];

    const int tid = threadIdx.x;
    const int tx = tid & 15, ty = tid >> 4;
    const long m0 = (long)blockIdx.x * 128;
    const long n0 = (long)blockIdx.y * 128;

    float acc[8][8];
#pragma unroll
    for (int i = 0; i < 8; ++i)
#pragma unroll
        for (int j = 0; j < 8; ++j) acc[i][j] = 0.f;

    for (int k0 = 0; k0 < Kc; k0 += 16) {
#pragma unroll
        for (int q = 0; q < 2; ++q) {
            int fi = tid + 256 * q, row = fi >> 2, col = (fi & 3) * 4;
            float4 v = *(const float4*)(A + (m0 + row) * (long)Kc + k0 + col);
            Asl[col + 0][row] = v.x; Asl[col + 1][row] = v.y;
            Asl[col + 2][row] = v.z; Asl[col + 3][row] = v.w;
        }
        if (BT) {
#pragma unroll
            for (int q = 0; q < 2; ++q) {
                int fi = tid + 256 * q, row = fi >> 2, col = (fi & 3) * 4;
                float4 v = *(const float4*)(B + (n0 + row) * (long)Kc + k0 + col);
                Bsl[col + 0][row] = v.x; Bsl[col + 1][row] = v.y;
                Bsl[col + 2][row] = v.z; Bsl[col + 3][row] = v.w;
            }
        } else {
#pragma unroll
            for (int q = 0; q < 2; ++q) {
                int fi = tid + 256 * q, row = fi >> 5, col = (fi & 31) * 4;
                float4 v = *(const float4*)(B + (k0 + row) * (long)N + n0 + col);
                *(float4*)&Bsl[row][col] = v;
            }
        }
        __syncthreads();
#pragma unroll
        for (int kk = 0; kk < 16; ++kk) {
            float a[8], b[8];
            *(float4*)&a[0] = *(const float4*)&Asl[kk][ty * 8];
            *(float4*)&a[4] = *(const float4*)&Asl[kk][ty * 8 + 4];
            *(float4*)&b[0] = *(const float4*)&Bsl[kk][tx * 8];
            *(float4*)&b[4] = *(const float4*)&Bsl[kk][tx * 8 + 4];
#pragma unroll
            for (int i = 0; i < 8; ++i)
#pragma unroll
                for (int j = 0; j < 8; ++j)
                    acc[i][j] = fmaf(a[i], b[j], acc[i][j]);
        }
        __syncthreads();
    }
#pragma unroll
    for (int i = 0; i < 8; ++i) {
        float* p = C + (m0 + ty * 8 + i) * (long)N + n0 + tx * 8;
        *(float4*)p       = make_float4(acc[i][0], acc[i][1], acc[i][2], acc[i][3]);
        *(float4*)(p + 4) = make_float4(acc[i][4], acc[i][5], acc[i][6], acc[i][7]);
    }
}

// ===========================================================================
// K1 with fused split-write: P = A@B (fp32 VALU), epilogue writes
// Ap = [P_hi | P_hi | P_lo] directly (no P materialization).
// ===========================================================================
__global__ __launch_bounds__(256)
void gemm128_hl(const float* __restrict__ A, const float* __restrict__ B,
                unsigned short* __restrict__ Ap, int M, int N, int Kc)
{
    __shared__ __align__(16) float Asl[16][132];
    __shared__ __align__(16) float Bsl[16][132];

    const int tid = threadIdx.x;
    const int tx = tid & 15, ty = tid >> 4;
    const long m0 = (long)blockIdx.x * 128;
    const long n0 = (long)blockIdx.y * 128;

    float acc[8][8];
#pragma unroll
    for (int i = 0; i < 8; ++i)
#pragma unroll
        for (int j = 0; j < 8; ++j) acc[i][j] = 0.f;

    for (int k0 = 0; k0 < Kc; k0 += 16) {
#pragma unroll
        for (int q = 0; q < 2; ++q) {
            int fi = tid + 256 * q, row = fi >> 2, col = (fi & 3) * 4;
            float4 v = *(const float4*)(A + (m0 + row) * (long)Kc + k0 + col);
            Asl[col + 0][row] = v.x; Asl[col + 1][row] = v.y;
            Asl[col + 2][row] = v.z; Asl[col + 3][row] = v.w;
        }
#pragma unroll
        for (int q = 0; q < 2; ++q) {
            int fi = tid + 256 * q, row = fi >> 5, col = (fi & 31) * 4;
            float4 v = *(const float4*)(B + (k0 + row) * (long)N + n0 + col);
            *(float4*)&Bsl[row][col] = v;
        }
        __syncthreads();
#pragma unroll
        for (int kk = 0; kk < 16; ++kk) {
            float a[8], b[8];
            *(float4*)&a[0] = *(const float4*)&Asl[kk][ty * 8];
            *(float4*)&a[4] = *(const float4*)&Asl[kk][ty * 8 + 4];
            *(float4*)&b[0] = *(const float4*)&Bsl[kk][tx * 8];
            *(float4*)&b[4] = *(const float4*)&Bsl[kk][tx * 8 + 4];
#pragma unroll
            for (int i = 0; i < 8; ++i)
#pragma unroll
                for (int j = 0; j < 8; ++j)
                    acc[i][j] = fmaf(a[i], b[j], acc[i][j]);
        }
        __syncthreads();
    }
#pragma unroll
    for (int i = 0; i < 8; ++i) {
        const long row = m0 + ty * 8 + i;
        const int  cb  = (int)n0 + tx * 8;
        u16x8 vh, vl;
#pragma unroll
        for (int j = 0; j < 8; ++j) {
            const float x = acc[i][j];
            const unsigned short hi = f2bf(x);
            vh[j] = hi;
            vl[j] = f2bf(x - bf2f(hi));
        }
        unsigned short* rp = Ap + row * KP;
        *(u16x8*)(rp + cb)             = vh;
        *(u16x8*)(rp + R_DIM + cb)     = vh;
        *(u16x8*)(rp + 2 * R_DIM + cb) = vl;
    }
}

// ---------------------------------------------------------------------------
// In-place row softmax (fallback path only)
// ---------------------------------------------------------------------------
__global__ __launch_bounds__(256)
void softmax_rows(float* __restrict__ Mio)
{
    const long n  = blockIdx.x;
    float* row    = Mio + n * (long)K_DIM;
    const int tid = threadIdx.x;

    float4 v[4];
    float lmax = -3.4e38f;
#pragma unroll
    for (int q = 0; q < 4; ++q) {
        v[q] = ((const float4*)row)[tid + 256 * q];
        lmax = fmaxf(lmax, fmaxf(fmaxf(v[q].x, v[q].y), fmaxf(v[q].z, v[q].w)));
    }
    __shared__ float redmax[4], redsum[4];
#pragma unroll
    for (int off = 32; off > 0; off >>= 1)
        lmax = fmaxf(lmax, __shfl_xor(lmax, off));
    if ((tid & 63) == 0) redmax[tid >> 6] = lmax;
    __syncthreads();
    const float gmax = fmaxf(fmaxf(redmax[0], redmax[1]), fmaxf(redmax[2], redmax[3]));

    float lsum = 0.f;
#pragma unroll
    for (int q = 0; q < 4; ++q) {
        v[q].x = __expf(v[q].x - gmax); v[q].y = __expf(v[q].y - gmax);
        v[q].z = __expf(v[q].z - gmax); v[q].w = __expf(v[q].w - gmax);
        lsum += v[q].x + v[q].y + v[q].z + v[q].w;
    }
#pragma unroll
    for (int off = 32; off > 0; off >>= 1)
        lsum += __shfl_xor(lsum, off);
    if ((tid & 63) == 0) redsum[tid >> 6] = lsum;
    __syncthreads();
    const float inv = 1.f / (redsum[0] + redsum[1] + redsum[2] + redsum[3]);
#pragma unroll
    for (int q = 0; q < 4; ++q) {
        v[q].x *= inv; v[q].y *= inv; v[q].z *= inv; v[q].w *= inv;
        ((float4*)row)[tid + 256 * q] = v[q];
    }
}

// ===========================================================================
extern "C" void kernel_launch(void* const* d_in, const int* in_sizes, int n_in,
                              void* d_out, int out_size, void* d_ws, size_t ws_size,
                              hipStream_t stream)
{
    const float* H  = (const float*)d_in[0];
    const float* L  = (const float*)d_in[1];
    const float* Wi = (const float*)d_in[2];

    float* Cout = (float*)d_out;                           // N x R
    float* Aout = (float*)d_out + (size_t)N_ROWS * R_DIM;  // N x K

    const size_t szAp = (size_t)N_ROWS * KP * 2;    // 48 MiB
    const size_t szBp = (size_t)K_DIM * KP * 2;     //  6 MiB
    const size_t szLT = (size_t)R_DIM * K_DIM * 2;  //  2 MiB
    const size_t szPm = (size_t)N_ROWS * KB * 4;    //  4 MiB
    const size_t szPs = (size_t)N_ROWS * KB * 4;    //  4 MiB
    const size_t szSM = (size_t)N_ROWS * 4;         // 128 KiB

    if (ws_size >= szAp + szBp + szLT + szPm + szPs + 2 * szSM) {
        char* w = (char*)d_ws;
        unsigned short* Ap = (unsigned short*)w;                 w += szAp;
        unsigned short* Bp = (unsigned short*)w;                 w += szBp;
        unsigned short* LT = (unsigned short*)w;                 w += szLT;
        float* Pm  = (float*)w;                                  w += szPm;
        float* Ps  = (float*)w;                                  w += szPs;
        float* SMm = (float*)w;                                  w += szSM;
        float* SMi = (float*)w;

        // K1: P = H@W_I (fp32 VALU), split [hi|hi|lo] written directly to Ap
        gemm128_hl<<<dim3(N_ROWS / 128, R_DIM / 128), 256, 0, stream>>>(
            H, Wi, Ap, N_ROWS, R_DIM, R_DIM);
        // Prep split B operand + transposed bf16 L
        prep_B<<<dim3((K_DIM * R_DIM) / 256), 256, 0, stream>>>(L, Bp);
        prep_LT<<<dim3((R_DIM * K_DIM) / 256), 256, 0, stream>>>(L, LT);
        // K2: logits (3-term split bf16 MFMA) -> e16 + softmax partials
        gemm_mfma_nt<<<dim3((N_ROWS / 128) * (K_DIM / 128)), 256, 0, stream>>>(
            Ap, Bp, Aout, Pm, Ps, N_ROWS, K_DIM, KP);
        // combine partials -> per-row stats; Ps rewritten in place as CS
        finalize_ms<<<dim3(N_ROWS / 256), 256, 0, stream>>>(Pm, Ps, SMm, SMi);
        // fused softmax-apply + PV from e16 (counted-vmcnt 2-phase, fixed)
        softmax_av_pv<<<dim3(N_ROWS / 64), 512, 0, stream>>>(
            Aout, LT, Ps, Cout);
    } else {
        // Fallback: round-1 fp32 path
        gemm128<false><<<dim3(N_ROWS / 128, R_DIM / 128), 256, 0, stream>>>(
            H, Wi, Cout, N_ROWS, R_DIM, R_DIM);
        gemm128<true><<<dim3(N_ROWS / 128, K_DIM / 128), 256, 0, stream>>>(
            Cout, L, Aout, N_ROWS, K_DIM, R_DIM);
        softmax_rows<<<dim3(N_ROWS), 256, 0, stream>>>(Aout);
        gemm128<false><<<dim3(N_ROWS / 128, R_DIM / 128), 256, 0, stream>>>(
            Aout, L, Cout, N_ROWS, R_DIM, K_DIM);
    }
}

// Round 14
// 1082.721 us; speedup vs baseline: 1.0189x; 1.0111x over previous
//
#include <hip/hip_runtime.h>
#include <hip/hip_bf16.h>
#include <math.h>
#include <stdint.h>

// Problem constants
constexpr int N_ROWS = 32768;
constexpr int K_DIM  = 4096;
constexpr int R_DIM  = 256;
constexpr int KP     = 3 * R_DIM;   // 768: split-K' for [hi|hi|lo] x [hi|lo|hi]
constexpr int KB     = K_DIM / 128; // 32 col-blocks in K2 grid

typedef __bf16 bf16x8 __attribute__((ext_vector_type(8)));
typedef float  f32x4  __attribute__((ext_vector_type(4)));
typedef unsigned short u16x8 __attribute__((ext_vector_type(8)));
typedef unsigned short u16x4 __attribute__((ext_vector_type(4)));

// ---- bf16 helpers (round-to-nearest-even; inputs are finite normals) ----
__device__ __forceinline__ unsigned short f2bf(float x) {
    unsigned u = __float_as_uint(x);
    u += 0x7fffu + ((u >> 16) & 1u);
    return (unsigned short)(u >> 16);
}
__device__ __forceinline__ float bf2f(unsigned short h) {
    return __uint_as_float((unsigned)h << 16);
}

// ---- async global->LDS, 16B per lane, LDS dest = wave-uniform base + lane*16
__device__ __forceinline__ void gl2lds16(const void* gptr, void* lptr) {
    __builtin_amdgcn_global_load_lds(
        (const __attribute__((address_space(1))) unsigned int*)gptr,
        (__attribute__((address_space(3))) unsigned int*)lptr,
        16, 0, 0);
}

// ===========================================================================
// K2: logits over A'(bf16 split) x B'^T. 128x128 tile, BK=32, 4 waves.
// Grid: 1-D, yb innermost (R10-proven). Chunk XOR-swizzle (R11-proven:
// bank conflicts 2.5e7 -> 0).
// NEW (T3-minimum 2-phase, catalog-proven +10% on grouped GEMM): LDS double-
// buffered; stage(t+1) issued BEFORE ds_read+MFMA(t); ONE __syncthreads per
// iteration (25 barriers vs 48). Stage latency hides under the compute phase;
// __syncthreads' vmcnt0+lgkm0 drain makes buffer-swap automatically safe
// (nxt fully staged; all ds_reads of cur retired before t+1 overwrites it).
// Epilogue (single-exp): block max, then ONE exp pass -> e16 + Ps partials.
// ===========================================================================
__global__ __launch_bounds__(256)
void gemm_mfma_nt(const unsigned short* __restrict__ A,
                  const unsigned short* __restrict__ B,
                  float* __restrict__ Mout,
                  float* __restrict__ Pm, float* __restrict__ Ps,
                  int M, int N, int Kc)
{
    __shared__ __align__(16) unsigned short As[2][128 * 32];  // 2 x 8 KiB
    __shared__ __align__(16) unsigned short Bs[2][128 * 32];  // 2 x 8 KiB
    __shared__ float pm_s[128][2], ps_s[128][2];
    __shared__ float pmc[128];

    const int tid  = threadIdx.x;
    const int wave = tid >> 6, lane = tid & 63;
    const int wm = wave >> 1, wn = wave & 1;

    // bijective 1-D decode: bid = xg*1024 + xi*32 + yb  (yb innermost)
    const int bid = blockIdx.x;
    const int xg = bid >> 10;          // row super-group 0..7
    const int xi = (bid >> 5) & 31;    // row-panel within group
    const int yb = bid & 31;           // col-panel     0..31
    const long m0 = (long)(xg * 32 + xi) * 128;
    const long n0 = (long)yb * 128;

    f32x4 acc[4][4] = {};

    const int srow  = lane >> 2;        // 0..15 within 16-row chunk
    // swizzled source elem offset: slot (l&3) of row (l>>2) loads global
    // 8-group (l&3) ^ ((row>>1)&3) = (l&3) ^ ((l>>3)&3)
    const int skoff = (((lane & 3) ^ ((lane >> 3) & 3)) * 8);
    const int c0 = wave, c1 = wave + 4; // each wave stages 2 chunks per tile
    const int mr = lane & 15;
    // swizzled fragment-read slot: global q = lane>>4 lives at slot q^((mr>>1)&3)
    const int kqs = (((lane >> 4) ^ ((mr >> 1) & 3)) * 8);

    // stage one BK=32 tile (A + B) into buffer buf
    auto stage = [&](int buf, int k0) {
        gl2lds16(A + (m0 + c0 * 16 + srow) * (long)Kc + k0 + skoff, &As[buf][c0 * 512]);
        gl2lds16(A + (m0 + c1 * 16 + srow) * (long)Kc + k0 + skoff, &As[buf][c1 * 512]);
        gl2lds16(B + (n0 + c0 * 16 + srow) * (long)Kc + k0 + skoff, &Bs[buf][c0 * 512]);
        gl2lds16(B + (n0 + c1 * 16 + srow) * (long)Kc + k0 + skoff, &Bs[buf][c1 * 512]);
    };

    // prologue: tile 0 staged and drained
    stage(0, 0);
    __syncthreads();

    const int NT = Kc / 32;   // 24
    for (int t = 0; t < NT; ++t) {
        const int cur = t & 1, nxt = cur ^ 1;
        if (t + 1 < NT) stage(nxt, (t + 1) * 32);   // flies under MFMA(cur)

        bf16x8 af[4], bfr[4];
#pragma unroll
        for (int tt = 0; tt < 4; ++tt) {
            af[tt]  = *(const bf16x8*)&As[cur][(wm * 64 + tt * 16 + mr) * 32 + kqs];
            bfr[tt] = *(const bf16x8*)&Bs[cur][(wn * 64 + tt * 16 + mr) * 32 + kqs];
        }
#pragma unroll
        for (int i = 0; i < 4; ++i)
#pragma unroll
            for (int j = 0; j < 4; ++j)
                acc[i][j] = __builtin_amdgcn_mfma_f32_16x16x32_bf16(
                    af[i], bfr[j], acc[i][j], 0, 0, 0);

        __syncthreads();   // single barrier: drains stage(nxt) + ds_reads(cur)
    }

    const int col = lane & 15, rquad = (lane >> 4) * 4;

    // ---- pass 1: wave-half max per row -> block max (pmc) + Pm -------------
#pragma unroll
    for (int i = 0; i < 4; ++i) {
#pragma unroll
        for (int r = 0; r < 4; ++r) {
            float mx = fmaxf(fmaxf(acc[i][0][r], acc[i][1][r]),
                             fmaxf(acc[i][2][r], acc[i][3][r]));
#pragma unroll
            for (int off = 1; off < 16; off <<= 1)
                mx = fmaxf(mx, __shfl_xor(mx, off));
            if (mr == 0) pm_s[wm * 64 + i * 16 + rquad + r][wn] = mx;
        }
    }
    __syncthreads();
    if (tid < 128) {
        const float mx = fmaxf(pm_s[tid][0], pm_s[tid][1]);
        pmc[tid] = mx;
        Pm[(m0 + tid) * KB + yb] = mx;
    }
    __syncthreads();

    // ---- pass 2: single exp pass -> e16 write + Ps sum partials ------------
    unsigned short* E = (unsigned short*)Mout;
#pragma unroll
    for (int i = 0; i < 4; ++i) {
#pragma unroll
        for (int r = 0; r < 4; ++r) {
            const int rw = wm * 64 + i * 16 + rquad + r;
            const float mx = pmc[rw];
            const float e0 = __expf(acc[i][0][r] - mx);
            const float e1 = __expf(acc[i][1][r] - mx);
            const float e2 = __expf(acc[i][2][r] - mx);
            const float e3 = __expf(acc[i][3][r] - mx);
            unsigned short* ep =
                E + (m0 + rw) * 8192L + 4096 + n0 + wn * 64 + col;
            ep[0]  = f2bf(e0); ep[16] = f2bf(e1);
            ep[32] = f2bf(e2); ep[48] = f2bf(e3);
            float sm = (e0 + e1) + (e2 + e3);
#pragma unroll
            for (int off = 1; off < 16; off <<= 1)
                sm += __shfl_xor(sm, off);
            if (mr == 0) ps_s[rw][wn] = sm;
        }
    }
    __syncthreads();
    if (tid < 128)
        Ps[(m0 + tid) * KB + yb] = ps_s[tid][0] + ps_s[tid][1];
}

// ===========================================================================
// Combine per-block softmax partials -> per-row (max, 1/sum) AND rewrite
// Ps in place as CS[n][b] = exp(Pm[n][b] - m_n) * inv_n (av_pv's rescales).
// ===========================================================================
__global__ __launch_bounds__(256)
void finalize_ms(const float* __restrict__ Pm, float* __restrict__ Ps,
                 float* __restrict__ SMm, float* __restrict__ SMi)
{
    const long row = (long)blockIdx.x * 256 + threadIdx.x;
    const float4* pm = (const float4*)(Pm + row * KB);
    float4* ps = (float4*)(Ps + row * KB);
    float4 v[8], w[8];
    float mx = -3.4e38f;
#pragma unroll
    for (int q = 0; q < 8; ++q) {
        v[q] = pm[q];
        w[q] = ps[q];
        mx = fmaxf(mx, fmaxf(fmaxf(v[q].x, v[q].y), fmaxf(v[q].z, v[q].w)));
    }
    float s = 0.f;
#pragma unroll
    for (int q = 0; q < 8; ++q) {
        s += w[q].x * __expf(v[q].x - mx) + w[q].y * __expf(v[q].y - mx) +
             w[q].z * __expf(v[q].z - mx) + w[q].w * __expf(v[q].w - mx);
    }
    const float inv = 1.f / s;
    SMm[row] = mx;
    SMi[row] = inv;
#pragma unroll
    for (int q = 0; q < 8; ++q) {
        float4 c;
        c.x = __expf(v[q].x - mx) * inv;
        c.y = __expf(v[q].y - mx) * inv;
        c.z = __expf(v[q].z - mx) * inv;
        c.w = __expf(v[q].w - mx) * inv;
        ps[q] = c;
    }
}

// ===========================================================================
// Fused softmax-apply + PV from e16 — counted-vmcnt 2-phase (R13-proven):
//   A[n,k] = bf2f(e16[n,k]) * CS[n][k/128]   (fp32, written over Aout rows)
//   C[n,r] = sum_k A[n,k] * LT[r,k]          (bf16 MFMA, A already normalized)
// Every iteration issues exactly 8 vmem ops (4 stage + 2 store + 2 clamped
// prefetch); vmcnt(4) at the barrier retires precisely the 4 pinned-oldest
// stage ops; stores+prefetch stay in flight across the barrier.
// ===========================================================================
__global__ __launch_bounds__(512, 4)
void softmax_av_pv(float* Aout,                      // NOT restrict: aliases e16
                   const unsigned short* __restrict__ LT,
                   const float* __restrict__ CS,
                   float* __restrict__ C)
{
    __shared__ __align__(16) unsigned short Bs[2][R_DIM * 64]; // 64 KiB (swizzled)
    __shared__ __align__(16) unsigned short As[2][64 * 64];    // 16 KiB (swizzled)

    const int tid  = threadIdx.x;
    const int wave = tid >> 6, lane = tid & 63;
    const long m0 = (long)blockIdx.x * 64;

    const int wm = wave >> 2, wn = wave & 3;  // wave tile: 32 rows x 64 cols
    const int mr = lane & 15;
    const int kq16 = (lane >> 4) * 16;

    // A-emit mapping: each thread owns 2 rows, 4 cols
    const int arow0 = wave * 4 + (lane >> 4);
    const int arow1 = 32 + arow0;
    const int acolE = (lane & 15) * 4;
    const unsigned short* const ep0 =
        (const unsigned short*)Aout + (m0 + arow0) * 8192L + 4096 + acolE;
    const unsigned short* const ep1 =
        (const unsigned short*)Aout + (m0 + arow1) * 8192L + 4096 + acolE;
    float* const gp0 = Aout + (m0 + arow0) * (long)K_DIM + acolE;
    float* const gp1 = Aout + (m0 + arow1) * (long)K_DIM + acolE;
    const int ab0 = (arow0 * 128 + acolE * 2) ^ ((arow0 & 7) << 4);
    const int ab1 = (arow1 * 128 + acolE * 2) ^ ((arow1 & 7) << 4);
    const float* const cs0 = CS + (m0 + arow0) * KB;
    const float* const cs1 = CS + (m0 + arow1) * KB;

    f32x4 acc[2][4] = {};
    constexpr int NT = K_DIM / 64;   // 64 tiles

    // stage LT k-tile into Bs[buf] (source pre-swizzled, dest linear)
    auto stage_B = [&](int buf, int k0) {
#pragma unroll
        for (int q = 0; q < 4; ++q) {
            const int rbase = q * 64 + wave * 8;
            const int rloc  = rbase + (lane >> 3);
            const int phys  = (lane & 7) * 16;
            const int kbyte = phys ^ ((rloc & 7) << 4);
            gl2lds16((const char*)LT + (long)rloc * (K_DIM * 2) + (long)k0 * 2 + kbyte,
                     &Bs[buf][rbase * 64]);
        }
    };
    // emit tile t1 into As[buf] from e16 regs: scale by CS, A-write, LDS bf16
    auto emit_A = [&](int buf, int t1, u16x4 va0, u16x4 va1) {
        const int b  = t1 >> 1;
        const int k0 = t1 * 64;
        const float c0 = cs0[b], c1 = cs1[b];
        float a0 = bf2f(va0[0]) * c0, a1 = bf2f(va0[1]) * c0;
        float a2 = bf2f(va0[2]) * c0, a3 = bf2f(va0[3]) * c0;
        *(float4*)(gp0 + k0) = make_float4(a0, a1, a2, a3);
        u16x4 u0;
        u0[0] = f2bf(a0); u0[1] = f2bf(a1); u0[2] = f2bf(a2); u0[3] = f2bf(a3);
        *(u16x4*)((char*)As[buf] + ab0) = u0;

        float b0 = bf2f(va1[0]) * c1, b1 = bf2f(va1[1]) * c1;
        float b2 = bf2f(va1[2]) * c1, b3 = bf2f(va1[3]) * c1;
        *(float4*)(gp1 + k0) = make_float4(b0, b1, b2, b3);
        u16x4 u1;
        u1[0] = f2bf(b0); u1[1] = f2bf(b1); u1[2] = f2bf(b2); u1[3] = f2bf(b3);
        *(u16x4*)((char*)As[buf] + ab1) = u1;
    };
    // counted-vmcnt barrier: the 4 stage ops (pinned oldest) retire; the
    // 2 stores + 2 prefetch loads (newest 4) may stay in flight.
    auto pipe_barrier = [&]() {
        asm volatile("s_waitcnt vmcnt(4) lgkmcnt(0)" ::: "memory");
        __builtin_amdgcn_s_barrier();
        __builtin_amdgcn_sched_barrier(0);
    };

    // --- prologue: tile 0 staged + emitted; e16(1) prefetched ---------------
    stage_B(0, 0);
    __builtin_amdgcn_sched_barrier(0);
    {
        u16x4 e0a = *(const u16x4*)ep0;
        u16x4 e0b = *(const u16x4*)ep1;
        emit_A(0, 0, e0a, e0b);
    }
    u16x4 va0 = *(const u16x4*)(ep0 + 64);   // e16(1)
    u16x4 va1 = *(const u16x4*)(ep1 + 64);
    pipe_barrier();

    for (int t = 0; t < NT; ++t) {
        const int cur = t & 1, nxt = cur ^ 1;
        if (t + 1 < NT) {
            stage_B(nxt, (t + 1) * 64);
            __builtin_amdgcn_sched_barrier(0);   // pin: stages issue first
            emit_A(nxt, t + 1, va0, va1);
        }
        // unconditional clamped prefetch keeps the vmcnt accounting uniform
        // (8 vmem ops/iter); tail loads are in-bounds and simply unconsumed.
        {
            const int tp = (t + 2 < NT) ? (t + 2) : (NT - 1);
            va0 = *(const u16x4*)(ep0 + tp * 64);
            va1 = *(const u16x4*)(ep1 + tp * 64);
        }

        // ---- MFMA on cur: 2x4 tiles x 2 k-slices ---------------------------
#pragma unroll
        for (int ks = 0; ks < 2; ++ks) {
            bf16x8 af[2], bfr[4];
#pragma unroll
            for (int tt = 0; tt < 2; ++tt) {
                const int ar = wm * 32 + tt * 16 + mr;
                const int ab = (ar * 128 + ks * 64 + kq16) ^ ((ar & 7) << 4);
                af[tt] = *(const bf16x8*)((const char*)As[cur] + ab);
            }
#pragma unroll
            for (int tt = 0; tt < 4; ++tt) {
                const int br = wn * 64 + tt * 16 + mr;
                const int bb = (br * 128 + ks * 64 + kq16) ^ ((br & 7) << 4);
                bfr[tt] = *(const bf16x8*)((const char*)Bs[cur] + bb);
            }
#pragma unroll
            for (int i = 0; i < 2; ++i)
#pragma unroll
                for (int j = 0; j < 4; ++j)
                    acc[i][j] = __builtin_amdgcn_mfma_f32_16x16x32_bf16(
                        af[i], bfr[j], acc[i][j], 0, 0, 0);
        }
        pipe_barrier();    // counted: stages done, stores/prefetch in flight
    }

    // ---- epilogue: A was already normalized -> C = acc directly ------------
    const int col = lane & 15, rquad = (lane >> 4) * 4;
#pragma unroll
    for (int i = 0; i < 2; ++i) {
        const int lrow0 = wm * 32 + i * 16 + rquad;
#pragma unroll
        for (int j = 0; j < 4; ++j) {
            float* p = C + (m0 + lrow0) * (long)R_DIM + wn * 64 + j * 16 + col;
#pragma unroll
            for (int r = 0; r < 4; ++r)
                p[(long)r * R_DIM] = acc[i][j][r];
        }
    }
}

// ===========================================================================
// Prep kernels
// ===========================================================================
// B' = [L_hi | L_lo | L_hi]  (K_DIM x 768)
__global__ __launch_bounds__(256)
void prep_B(const float* __restrict__ L, unsigned short* __restrict__ Bp)
{
    const long i = (long)blockIdx.x * 256 + threadIdx.x;   // over K_DIM*R_DIM
    const long k = i >> 8; const int r = (int)(i & 255);
    const float x = L[i];
    const unsigned short hi = f2bf(x);
    const unsigned short lo = f2bf(x - bf2f(hi));
    unsigned short* row = Bp + k * KP;
    row[r] = hi; row[R_DIM + r] = lo; row[2 * R_DIM + r] = hi;
}

// LT[r][k] = bf16(L[k][r])  (256 x 4096) — coalesced writes
__global__ __launch_bounds__(256)
void prep_LT(const float* __restrict__ L, unsigned short* __restrict__ LT)
{
    const long i = (long)blockIdx.x * 256 + threadIdx.x;   // over R_DIM*K_DIM
    const long r = i >> 12; const long k = i & 4095;
    LT[r * K_DIM + k] = f2bf(L[k * R_DIM + r]);
}

// ===========================================================================
// fp32 VALU GEMM — K1 base + fallback path.
// ===========================================================================
template<bool BT>
__global__ __launch_bounds__(256)
void gemm128(const float* __restrict__ A, const float* __restrict__ B,
             float* __restrict__ C, int M, int N, int Kc)
{
    __shared__ __align__(16) float Asl[16][132];
    __shared__ __align__(16) float Bsl[16][132];

    const int tid = threadIdx.x;
    const int tx = tid & 15, ty = tid >> 4;
    const long m0 = (long)blockIdx.x * 128;
    const long n0 = (long)blockIdx.y * 128;

    float acc[8][8];
#pragma unroll
    for (int i = 0; i < 8; ++i)
#pragma unroll
        for (int j = 0; j < 8; ++j) acc[i][j] = 0.f;

    for (int k0 = 0; k0 < Kc; k0 += 16) {
#pragma unroll
        for (int q = 0; q < 2; ++q) {
            int fi = tid + 256 * q, row = fi >> 2, col = (fi & 3) * 4;
            float4 v = *(const float4*)(A + (m0 + row) * (long)Kc + k0 + col);
            Asl[col + 0][row] = v.x; Asl[col + 1][row] = v.y;
            Asl[col + 2][row] = v.z; Asl[col + 3][row] = v.w;
        }
        if (BT) {
#pragma unroll
            for (int q = 0; q < 2; ++q) {
                int fi = tid + 256 * q, row = fi >> 2, col = (fi & 3) * 4;
                float4 v = *(const float4*)(B + (n0 + row) * (long)Kc + k0 + col);
                Bsl[col + 0][row] = v.x; Bsl[col + 1][row] = v.y;
                Bsl[col + 2][row] = v.z; Bsl[col + 3][row] = v.w;
            }
        } else {
#pragma unroll
            for (int q = 0; q < 2; ++q) {
                int fi = tid + 256 * q, row = fi >> 5, col = (fi & 31) * 4;
                float4 v = *(const float4*)(B + (k0 + row) * (long)N + n0 + col);
                *(float4*)&Bsl[row][col] = v;
            }
        }
        __syncthreads();
#pragma unroll
        for (int kk = 0; kk < 16; ++kk) {
            float a[8], b[8];
            *(float4*)&a[0] = *(const float4*)&Asl[kk][ty * 8];
            *(float4*)&a[4] = *(const float4*)&Asl[kk][ty * 8 + 4];
            *(float4*)&b[0] = *(const float4*)&Bsl[kk][tx * 8];
            *(float4*)&b[4] = *(const float4*)&Bsl[kk][tx * 8 + 4];
#pragma unroll
            for (int i = 0; i < 8; ++i)
#pragma unroll
                for (int j = 0; j < 8; ++j)
                    acc[i][j] = fmaf(a[i], b[j], acc[i][j]);
        }
        __syncthreads();
    }
#pragma unroll
    for (int i = 0; i < 8; ++i) {
        float* p = C + (m0 + ty * 8 + i) * (long)N + n0 + tx * 8;
        *(float4*)p       = make_float4(acc[i][0], acc[i][1], acc[i][2], acc[i][3]);
        *(float4*)(p + 4) = make_float4(acc[i][4], acc[i][5], acc[i][6], acc[i][7]);
    }
}

// ===========================================================================
// K1 with fused split-write: P = A@B (fp32 VALU), epilogue writes
// Ap = [P_hi | P_hi | P_lo] directly (no P materialization).
// ===========================================================================
__global__ __launch_bounds__(256)
void gemm128_hl(const float* __restrict__ A, const float* __restrict__ B,
                unsigned short* __restrict__ Ap, int M, int N, int Kc)
{
    __shared__ __align__(16) float Asl[16][132];
    __shared__ __align__(16) float Bsl[16][132];

    const int tid = threadIdx.x;
    const int tx = tid & 15, ty = tid >> 4;
    const long m0 = (long)blockIdx.x * 128;
    const long n0 = (long)blockIdx.y * 128;

    float acc[8][8];
#pragma unroll
    for (int i = 0; i < 8; ++i)
#pragma unroll
        for (int j = 0; j < 8; ++j) acc[i][j] = 0.f;

    for (int k0 = 0; k0 < Kc; k0 += 16) {
#pragma unroll
        for (int q = 0; q < 2; ++q) {
            int fi = tid + 256 * q, row = fi >> 2, col = (fi & 3) * 4;
            float4 v = *(const float4*)(A + (m0 + row) * (long)Kc + k0 + col);
            Asl[col + 0][row] = v.x; Asl[col + 1][row] = v.y;
            Asl[col + 2][row] = v.z; Asl[col + 3][row] = v.w;
        }
#pragma unroll
        for (int q = 0; q < 2; ++q) {
            int fi = tid + 256 * q, row = fi >> 5, col = (fi & 31) * 4;
            float4 v = *(const float4*)(B + (k0 + row) * (long)N + n0 + col);
            *(float4*)&Bsl[row][col] = v;
        }
        __syncthreads();
#pragma unroll
        for (int kk = 0; kk < 16; ++kk) {
            float a[8], b[8];
            *(float4*)&a[0] = *(const float4*)&Asl[kk][ty * 8];
            *(float4*)&a[4] = *(const float4*)&Asl[kk][ty * 8 + 4];
            *(float4*)&b[0] = *(const float4*)&Bsl[kk][tx * 8];
            *(float4*)&b[4] = *(const float4*)&Bsl[kk][tx * 8 + 4];
#pragma unroll
            for (int i = 0; i < 8; ++i)
#pragma unroll
                for (int j = 0; j < 8; ++j)
                    acc[i][j] = fmaf(a[i], b[j], acc[i][j]);
        }
        __syncthreads();
    }
#pragma unroll
    for (int i = 0; i < 8; ++i) {
        const long row = m0 + ty * 8 + i;
        const int  cb  = (int)n0 + tx * 8;
        u16x8 vh, vl;
#pragma unroll
        for (int j = 0; j < 8; ++j) {
            const float x = acc[i][j];
            const unsigned short hi = f2bf(x);
            vh[j] = hi;
            vl[j] = f2bf(x - bf2f(hi));
        }
        unsigned short* rp = Ap + row * KP;
        *(u16x8*)(rp + cb)             = vh;
        *(u16x8*)(rp + R_DIM + cb)     = vh;
        *(u16x8*)(rp + 2 * R_DIM + cb) = vl;
    }
}

// ---------------------------------------------------------------------------
// In-place row softmax (fallback path only)
// ---------------------------------------------------------------------------
__global__ __launch_bounds__(256)
void softmax_rows(float* __restrict__ Mio)
{
    const long n  = blockIdx.x;
    float* row    = Mio + n * (long)K_DIM;
    const int tid = threadIdx.x;

    float4 v[4];
    float lmax = -3.4e38f;
#pragma unroll
    for (int q = 0; q < 4; ++q) {
        v[q] = ((const float4*)row)[tid + 256 * q];
        lmax = fmaxf(lmax, fmaxf(fmaxf(v[q].x, v[q].y), fmaxf(v[q].z, v[q].w)));
    }
    __shared__ float redmax[4], redsum[4];
#pragma unroll
    for (int off = 32; off > 0; off >>= 1)
        lmax = fmaxf(lmax, __shfl_xor(lmax, off));
    if ((tid & 63) == 0) redmax[tid >> 6] = lmax;
    __syncthreads();
    const float gmax = fmaxf(fmaxf(redmax[0], redmax[1]), fmaxf(redmax[2], redmax[3]));

    float lsum = 0.f;
#pragma unroll
    for (int q = 0; q < 4; ++q) {
        v[q].x = __expf(v[q].x - gmax); v[q].y = __expf(v[q].y - gmax);
        v[q].z = __expf(v[q].z - gmax); v[q].w = __expf(v[q].w - gmax);
        lsum += v[q].x + v[q].y + v[q].z + v[q].w;
    }
#pragma unroll
    for (int off = 32; off > 0; off >>= 1)
        lsum += __shfl_xor(lsum, off);
    if ((tid & 63) == 0) redsum[tid >> 6] = lsum;
    __syncthreads();
    const float inv = 1.f / (redsum[0] + redsum[1] + redsum[2] + redsum[3]);
#pragma unroll
    for (int q = 0; q < 4; ++q) {
        v[q].x *= inv; v[q].y *= inv; v[q].z *= inv; v[q].w *= inv;
        ((float4*)row)[tid + 256 * q] = v[q];
    }
}

// ===========================================================================
extern "C" void kernel_launch(void* const* d_in, const int* in_sizes, int n_in,
                              void* d_out, int out_size, void* d_ws, size_t ws_size,
                              hipStream_t stream)
{
    const float* H  = (const float*)d_in[0];
    const float* L  = (const float*)d_in[1];
    const float* Wi = (const float*)d_in[2];

    float* Cout = (float*)d_out;                           // N x R
    float* Aout = (float*)d_out + (size_t)N_ROWS * R_DIM;  // N x K

    const size_t szAp = (size_t)N_ROWS * KP * 2;    // 48 MiB
    const size_t szBp = (size_t)K_DIM * KP * 2;     //  6 MiB
    const size_t szLT = (size_t)R_DIM * K_DIM * 2;  //  2 MiB
    const size_t szPm = (size_t)N_ROWS * KB * 4;    //  4 MiB
    const size_t szPs = (size_t)N_ROWS * KB * 4;    //  4 MiB
    const size_t szSM = (size_t)N_ROWS * 4;         // 128 KiB

    if (ws_size >= szAp + szBp + szLT + szPm + szPs + 2 * szSM) {
        char* w = (char*)d_ws;
        unsigned short* Ap = (unsigned short*)w;                 w += szAp;
        unsigned short* Bp = (unsigned short*)w;                 w += szBp;
        unsigned short* LT = (unsigned short*)w;                 w += szLT;
        float* Pm  = (float*)w;                                  w += szPm;
        float* Ps  = (float*)w;                                  w += szPs;
        float* SMm = (float*)w;                                  w += szSM;
        float* SMi = (float*)w;

        // K1: P = H@W_I (fp32 VALU), split [hi|hi|lo] written directly to Ap
        gemm128_hl<<<dim3(N_ROWS / 128, R_DIM / 128), 256, 0, stream>>>(
            H, Wi, Ap, N_ROWS, R_DIM, R_DIM);
        // Prep split B operand + transposed bf16 L
        prep_B<<<dim3((K_DIM * R_DIM) / 256), 256, 0, stream>>>(L, Bp);
        prep_LT<<<dim3((R_DIM * K_DIM) / 256), 256, 0, stream>>>(L, LT);
        // K2: logits (3-term split bf16 MFMA) -> e16 + softmax partials
        // T3-minimum 2-phase double-buffer: stage(t+1) hides under MFMA(t)
        gemm_mfma_nt<<<dim3((N_ROWS / 128) * (K_DIM / 128)), 256, 0, stream>>>(
            Ap, Bp, Aout, Pm, Ps, N_ROWS, K_DIM, KP);
        // combine partials -> per-row stats; Ps rewritten in place as CS
        finalize_ms<<<dim3(N_ROWS / 256), 256, 0, stream>>>(Pm, Ps, SMm, SMi);
        // fused softmax-apply + PV from e16 (counted-vmcnt 2-phase)
        softmax_av_pv<<<dim3(N_ROWS / 64), 512, 0, stream>>>(
            Aout, LT, Ps, Cout);
    } else {
        // Fallback: round-1 fp32 path
        gemm128<false><<<dim3(N_ROWS / 128, R_DIM / 128), 256, 0, stream>>>(
            H, Wi, Cout, N_ROWS, R_DIM, R_DIM);
        gemm128<true><<<dim3(N_ROWS / 128, K_DIM / 128), 256, 0, stream>>>(
            Cout, L, Aout, N_ROWS, K_DIM, R_DIM);
        softmax_rows<<<dim3(N_ROWS), 256, 0, stream>>>(Aout);
        gemm128<false><<<dim3(N_ROWS / 128, R_DIM / 128), 256, 0, stream>>>(
            Aout, L, Cout, N_ROWS, R_DIM, K_DIM);
    }
}